// Round 23
// baseline (4471.804 us; speedup 1.0000x reference)
//
#include <hip/hip_runtime.h>

#define DEVINL __device__ __forceinline__

// Problem constants
constexpr int kB = 4, kT = 256, kH = 256, kA = 256, kV = 32000;
constexpr int NBLKS = 128;  // 4 groups x 32 blocks (one batch per group)
constexpr int NGRP = 32;    // blocks per group == contributors per score slot
constexpr int NTHR = 512;   // 8 waves per block
constexpr int WSL = 8;      // column-slice width = 256 / 32
constexpr int SBIAS = 1 << 24;             // per-contribution bias == arrival count unit
constexpr int SBIAS_TOT = NGRP * SBIAS;    // 2^29, subtract at read
constexpr unsigned long long CANARY = ~0ull;  // NaN|NaN — unreachable by finite nh pairs

typedef __attribute__((ext_vector_type(8))) short bf16x8;
typedef __attribute__((ext_vector_type(4))) float f32x4;

// ---------------- fast math helpers -----------------------------------------
DEVINL float fexp2(float x) { float y; asm("v_exp_f32 %0, %1" : "=v"(y) : "v"(x)); return y; }
DEVINL float frcp(float x)  { float y; asm("v_rcp_f32 %0, %1" : "=v"(y) : "v"(x)); return y; }
DEVINL float f_tanh(float x) {
  float t = fexp2(x * 2.88539008f);           // e^{2x}
  return 1.f - 2.f * frcp(t + 1.f);
}
DEVINL float f_sig(float x) { return frcp(1.f + fexp2(-x * 1.44269504f)); }

DEVINL float bfu2f(unsigned short u) {
  union { unsigned int i; float f; } c; c.i = ((unsigned int)u) << 16; return c.f;
}
DEVINL unsigned short f2bfu(float f) {
  union { float f; unsigned int i; } c; c.f = f;
  unsigned int r = c.i + 0x7fffu + ((c.i >> 16) & 1u);   // RNE
  return (unsigned short)(r >> 16);
}
DEVINL unsigned int f2u(float f) { union { float f; unsigned int i; } c; c.f = f; return c.i; }
DEVINL float u2f(unsigned int u) { union { unsigned int i; float f; } c; c.i = u; return c.f; }

// coherent (agent-scope, memory-side) access helpers — all RELAXED
DEVINL unsigned long long aload64(const unsigned long long* p) {
  return __hip_atomic_load(p, __ATOMIC_RELAXED, __HIP_MEMORY_SCOPE_AGENT);
}
DEVINL void astore64(unsigned long long* p, unsigned long long v) {
  __hip_atomic_store(p, v, __ATOMIC_RELAXED, __HIP_MEMORY_SCOPE_AGENT);
}

// score slot readiness: each 32-bit field carries count*2^24 + val (|val|<2^23)
DEVINL bool sready(unsigned long long v) {
  unsigned int lo = (unsigned int)v, hi = (unsigned int)(v >> 32);
  return (((lo + (1u << 23)) >> 24) == (unsigned)NGRP) &&
         (((hi + (1u << 23)) >> 24) == (unsigned)NGRP);
}

// STRIDED quarter-dot: quarter q processes ushort4-chunks q, q+4, ..., q+60.
// Chunk offset q*8B = 2 banks -> the 4 quarters hit DISTINCT banks.
DEVINL float dot_bf64s(const float* x, const unsigned short* w, int q) {
  float a0 = 0.f, a1 = 0.f, a2 = 0.f, a3 = 0.f;
  const float4*  x4 = (const float4*)x;
  const ushort4* w4 = (const ushort4*)w;
#pragma unroll
  for (int i = 0; i < 16; ++i) {
    int c = q + 4 * i;
    float4 xv = x4[c]; ushort4 wv = w4[c];
    a0 += xv.x * bfu2f(wv.x);
    a1 += xv.y * bfu2f(wv.y);
    a2 += xv.z * bfu2f(wv.z);
    a3 += xv.w * bfu2f(wv.w);
  }
  return (a0 + a1) + (a2 + a3);
}

// Same quarter-dot but x read DIRECTLY from a canary-tagged packed global row
// (nh1p row: element pair 2c,2c+1 per u64). Accumulation order IDENTICAL to
// dot_bf64s (element 4c+j -> accumulator j). Data is one step old -> polls
// return immediately in steady state.
DEVINL float dot_nh1g(const unsigned long long* xrow, const unsigned short* w, int q) {
  float a0 = 0.f, a1 = 0.f, a2 = 0.f, a3 = 0.f;
  const ushort4* w4 = (const ushort4*)w;
#pragma unroll
  for (int i = 0; i < 16; ++i) {
    int c = q + 4 * i;
    unsigned long long va = aload64(xrow + 2 * c);
    int it = 0;
    while (va == CANARY) { va = aload64(xrow + 2 * c); if (++it > (1 << 24)) break; }
    unsigned long long vb = aload64(xrow + 2 * c + 1);
    it = 0;
    while (vb == CANARY) { vb = aload64(xrow + 2 * c + 1); if (++it > (1 << 24)) break; }
    ushort4 wv = w4[c];
    a0 += u2f((unsigned int)va)         * bfu2f(wv.x);
    a1 += u2f((unsigned int)(va >> 32)) * bfu2f(wv.y);
    a2 += u2f((unsigned int)vb)         * bfu2f(wv.z);
    a3 += u2f((unsigned int)(vb >> 32)) * bfu2f(wv.w);
  }
  return (a0 + a1) + (a2 + a3);
}

// 4-term tanh score partial, 2 accumulators
DEVINL float sc4(const unsigned short* p4p, const float* xp, const float* vr) {
  ushort4 p4 = *(const ushort4*)p4p;
  float accA, accB;
  accA  = f_tanh(bfu2f(p4.x) + xp[0]) * vr[0];
  accB  = f_tanh(bfu2f(p4.y) + xp[1]) * vr[1];
  accA += f_tanh(bfu2f(p4.z) + xp[2]) * vr[2];
  accB += f_tanh(bfu2f(p4.w) + xp[3]) * vr[3];
  return accA + accB;
}

// ---------------- small kernels ----------------------------------------------
__global__ void init_kernel(int* dst, int nz, int val) {
  for (int i = blockIdx.x * blockDim.x + threadIdx.x; i < nz; i += gridDim.x * blockDim.x)
    dst[i] = val;
}

__global__ void embed_kernel(const int* __restrict__ ids, const int* __restrict__ cids,
                             const float* __restrict__ emb, const float* __restrict__ cat_emb,
                             unsigned short* __restrict__ li0bf, float* __restrict__ ce_all,
                             float* __restrict__ cat1_all) {
  int bt = blockIdx.x, e = threadIdx.x;
  int id = ids[bt], cid = cids[bt];
  float we = emb[id * kH + e];
  float ce = cat_emb[cid * kH + e];
  li0bf[bt * 512 + e]       = f2bfu(fmaxf(we + ce, 0.f));
  li0bf[bt * 512 + 256 + e] = f2bfu(fmaxf(ce + ce, 0.f));
  ce_all[bt * 256 + e] = ce;
  cat1_all[bt * 512 + 256 + e] = ce;   // upper half of [nh1, ce] concat
}

// ---------------- MFMA GEMM: C = A_bf16[1024,512] @ W[512,N] + bias (f32 out)
// One 64x64 tile per block; W panel staged f32->bf16 in LDS.
__global__ __launch_bounds__(256) void gemm_mfma_f32out(
    const unsigned short* __restrict__ A,    // [1024][512] bf16
    const float* __restrict__ Wm,            // [512][N] f32
    const float* __restrict__ bias,          // [N]
    float* __restrict__ C, int N) {          // [1024][N]
  __shared__ __align__(16) unsigned short Bt[64][520];
  const int tid = threadIdx.x;
  const int n0 = blockIdx.x * 64, m0 = blockIdx.y * 64;

  for (int idx = tid; idx < 512 * 16; idx += 256) {
    int k = idx >> 4, nq = (idx & 15) << 2;
    float4 v = *(const float4*)(Wm + (size_t)k * N + n0 + nq);
    Bt[nq + 0][k] = f2bfu(v.x); Bt[nq + 1][k] = f2bfu(v.y);
    Bt[nq + 2][k] = f2bfu(v.z); Bt[nq + 3][k] = f2bfu(v.w);
  }
  __syncthreads();

  const int l = tid & 63, w = tid >> 6;
  const int lrow = l & 15, lk = (l >> 4) * 8;
  float bia0 = bias[n0 +  0 + lrow];
  float bia1 = bias[n0 + 16 + lrow];
  float bia2 = bias[n0 + 32 + lrow];
  float bia3 = bias[n0 + 48 + lrow];

  f32x4 acc0 = {0.f, 0.f, 0.f, 0.f}, acc1 = acc0, acc2 = acc0, acc3 = acc0;
  const unsigned short* Arow = A + (size_t)(m0 + w * 16 + lrow) * 512 + lk;
#pragma unroll
  for (int ks = 0; ks < 16; ++ks) {
    bf16x8 a  = *(const bf16x8*)(Arow + ks * 32);
    bf16x8 b0 = *(const bf16x8*)&Bt[ 0 + lrow][ks * 32 + lk];
    bf16x8 b1 = *(const bf16x8*)&Bt[16 + lrow][ks * 32 + lk];
    bf16x8 b2 = *(const bf16x8*)&Bt[32 + lrow][ks * 32 + lk];
    bf16x8 b3 = *(const bf16x8*)&Bt[48 + lrow][ks * 32 + lk];
    acc0 = __builtin_amdgcn_mfma_f32_16x16x32_bf16(a, b0, acc0, 0, 0, 0);
    acc1 = __builtin_amdgcn_mfma_f32_16x16x32_bf16(a, b1, acc1, 0, 0, 0);
    acc2 = __builtin_amdgcn_mfma_f32_16x16x32_bf16(a, b2, acc2, 0, 0, 0);
    acc3 = __builtin_amdgcn_mfma_f32_16x16x32_bf16(a, b3, acc3, 0, 0, 0);
  }
  int orow = m0 + w * 16 + (l >> 4) * 4;
#pragma unroll
  for (int r = 0; r < 4; ++r) {
    float* Cr = C + (size_t)(orow + r) * N + n0;
    Cr[ 0 + lrow] = acc0[r] + bia0;
    Cr[16 + lrow] = acc1[r] + bia1;
    Cr[32 + lrow] = acc2[r] + bia2;
    Cr[48 + lrow] = acc3[r] + bia3;
  }
}

// ---------------- ctx GEMM: ctx_bf = bf16(tanh(cat1 @ Wctx + bctx)) ----------
__global__ __launch_bounds__(256) void gemm_ctx_bf16(const float* __restrict__ A,
                                                     const float* __restrict__ Wm,
                                                     const float* __restrict__ bias,
                                                     unsigned short* __restrict__ Cb) {
  const int N = 500, K = 512;
  __shared__ __align__(16) float As[16][68];
  __shared__ __align__(16) float Bs[16][68];
  int tid = threadIdx.x;
  int tx = tid & 15, ty = tid >> 4;
  int row0 = blockIdx.y * 64, col0 = blockIdx.x * 64;
  int ar = tid >> 2;
  int ak = (tid & 3) * 4;
  int br = tid >> 4;
  int bc = (tid & 15) * 4;
  float acc[4][4] = {};
  for (int k0 = 0; k0 < K; k0 += 16) {
    float4 av = *(const float4*)(A + (size_t)(row0 + ar) * K + k0 + ak);
    As[ak + 0][ar] = av.x; As[ak + 1][ar] = av.y; As[ak + 2][ar] = av.z; As[ak + 3][ar] = av.w;
    float4 bv = {0.f, 0.f, 0.f, 0.f};
    int wrow = k0 + br;
    if (col0 + bc + 3 < N) bv = *(const float4*)(Wm + (size_t)wrow * N + col0 + bc);
    else {
      float t[4] = {0.f, 0.f, 0.f, 0.f};
      for (int u = 0; u < 4; ++u) if (col0 + bc + u < N) t[u] = Wm[(size_t)wrow * N + col0 + bc + u];
      bv.x = t[0]; bv.y = t[1]; bv.z = t[2]; bv.w = t[3];
    }
    *(float4*)&Bs[br][bc] = bv;
    __syncthreads();
#pragma unroll
    for (int kk = 0; kk < 16; ++kk) {
      float4 a4 = *(const float4*)&As[kk][ty * 4];
      float4 b4 = *(const float4*)&Bs[kk][tx * 4];
      acc[0][0] += a4.x * b4.x; acc[0][1] += a4.x * b4.y; acc[0][2] += a4.x * b4.z; acc[0][3] += a4.x * b4.w;
      acc[1][0] += a4.y * b4.x; acc[1][1] += a4.y * b4.y; acc[1][2] += a4.y * b4.z; acc[1][3] += a4.y * b4.w;
      acc[2][0] += a4.z * b4.x; acc[2][1] += a4.z * b4.y; acc[2][2] += a4.z * b4.z; acc[2][3] += a4.z * b4.w;
      acc[3][0] += a4.w * b4.x; acc[3][1] += a4.w * b4.y; acc[3][2] += a4.w * b4.z; acc[3][3] += a4.w * b4.w;
    }
    __syncthreads();
  }
#pragma unroll
  for (int i = 0; i < 4; ++i) {
    int r = row0 + ty * 4 + i;
#pragma unroll
    for (int j = 0; j < 4; ++j) {
      int c = col0 + tx * 4 + j;
      if (c < N) {
        float v = f_tanh(acc[i][j] + bias[c]);
        Cb[(size_t)r * 512 + c] = f2bfu(v);
      } else {
        Cb[(size_t)r * 512 + c] = 0;
      }
    }
  }
}

// ---------------- logits GEMM via MFMA bf16 ----------------------------------
__global__ __launch_bounds__(256) void gemm_logits_mfma(
    const unsigned short* __restrict__ A,    // ctx_bf [1024][512] bf16 (K-padded)
    const float* __restrict__ Wout,          // [500][32000] f32
    const float* __restrict__ bout,          // [32000]
    float* __restrict__ C) {                 // [1024][32000]
  __shared__ __align__(16) unsigned short Bt[64][520];
  const int tid = threadIdx.x;
  const int n0 = blockIdx.x * 64;

  for (int idx = tid; idx < 512 * 16; idx += 256) {
    int k = idx >> 4, nq = (idx & 15) << 2;
    if (k < 500) {
      float4 v = *(const float4*)(Wout + (size_t)k * 32000 + n0 + nq);
      Bt[nq + 0][k] = f2bfu(v.x); Bt[nq + 1][k] = f2bfu(v.y);
      Bt[nq + 2][k] = f2bfu(v.z); Bt[nq + 3][k] = f2bfu(v.w);
    } else {
      Bt[nq + 0][k] = 0; Bt[nq + 1][k] = 0; Bt[nq + 2][k] = 0; Bt[nq + 3][k] = 0;
    }
  }
  __syncthreads();

  const int l = tid & 63, w = tid >> 6;
  const int lrow = l & 15, lk = (l >> 4) * 8;
  float bia0 = bout[n0 +  0 + lrow];
  float bia1 = bout[n0 + 16 + lrow];
  float bia2 = bout[n0 + 32 + lrow];
  float bia3 = bout[n0 + 48 + lrow];

  for (int m0 = 0; m0 < 1024; m0 += 64) {
    f32x4 acc0 = {0.f, 0.f, 0.f, 0.f}, acc1 = acc0, acc2 = acc0, acc3 = acc0;
    const unsigned short* Arow = A + (size_t)(m0 + w * 16 + lrow) * 512 + lk;
#pragma unroll
    for (int ks = 0; ks < 16; ++ks) {
      bf16x8 a  = *(const bf16x8*)(Arow + ks * 32);
      bf16x8 b0 = *(const bf16x8*)&Bt[ 0 + lrow][ks * 32 + lk];
      bf16x8 b1 = *(const bf16x8*)&Bt[16 + lrow][ks * 32 + lk];
      bf16x8 b2 = *(const bf16x8*)&Bt[32 + lrow][ks * 32 + lk];
      bf16x8 b3 = *(const bf16x8*)&Bt[48 + lrow][ks * 32 + lk];
      acc0 = __builtin_amdgcn_mfma_f32_16x16x32_bf16(a, b0, acc0, 0, 0, 0);
      acc1 = __builtin_amdgcn_mfma_f32_16x16x32_bf16(a, b1, acc1, 0, 0, 0);
      acc2 = __builtin_amdgcn_mfma_f32_16x16x32_bf16(a, b2, acc2, 0, 0, 0);
      acc3 = __builtin_amdgcn_mfma_f32_16x16x32_bf16(a, b3, acc3, 0, 0, 0);
    }
    int orow = m0 + w * 16 + (l >> 4) * 4;
#pragma unroll
    for (int r = 0; r < 4; ++r) {
      float* Cr = C + (size_t)(orow + r) * 32000 + n0;
      Cr[ 0 + lrow] = acc0[r] + bia0;
      Cr[16 + lrow] = acc1[r] + bia1;
      Cr[32 + lrow] = acc2[r] + bia2;
      Cr[48 + lrow] = acc3[r] + bia3;
    }
  }
}

// ---------------- persistent cooperative recurrence kernel -------------------
// FULL DATAFLOW — zero grid barriers. 4 INDEPENDENT groups x 32 blocks, one
// BATCH per group. Block owns 8 a/h-cols. Phase A overlaps the nh0(k) poll
// with the 40 L1-recurrent dots (which read year-old nh1(k-1) straight from
// the tagged global slots — numerically identical order). Score fan-in:
// count-embedded u64 atomics, parity-3. nh broadcast: packed f32-pair+canary.
__global__ __launch_bounds__(NTHR, 1) void coop_kernel(
    const float* __restrict__ gi0_all, const float* __restrict__ xw0_all,
    const float* __restrict__ ce_all,
    unsigned long long* __restrict__ nh0p, unsigned long long* __restrict__ nh1p,
    float* __restrict__ cat1_all, float* __restrict__ out_tail,
    unsigned long long* __restrict__ s0buf, unsigned long long* __restrict__ s1buf,
    const float* __restrict__ Whh0, const float* __restrict__ bhh0,
    const float* __restrict__ Wh0, const float* __restrict__ bh0,
    const float* __restrict__ Wth0, const float* __restrict__ bth0,
    const float* __restrict__ v0,
    const float* __restrict__ Wih1, const float* __restrict__ bih1,
    const float* __restrict__ Whh1, const float* __restrict__ bhh1,
    const float* __restrict__ Wh1, const float* __restrict__ bh1,
    const float* __restrict__ Wx1, const float* __restrict__ bx1,
    const float* __restrict__ Wth1, const float* __restrict__ bth1,
    const float* __restrict__ v1) {
  // ---- persistent LDS (~105 KB) ----
  __shared__ __align__(16) unsigned short tWhh0_s[kT][24];   // [j][cc] bf16
  __shared__ __align__(16) unsigned short tWhh1_s[kT][24];
  __shared__ __align__(16) unsigned short tape0_s[kT][8];    // [j][c] bf16
  __shared__ __align__(16) unsigned short tape1_s[kT][8];
  __shared__ __align__(16) unsigned short tWh0_s[kT][8];     // [j][c] bf16
  __shared__ __align__(16) unsigned short tWh1_s[kT][8];
  // weight column-slices (bf16, padded rows of 264)
  __shared__ __align__(16) unsigned short Wh0c[WSL][264], Wth0c[WSL][264];
  __shared__ __align__(16) unsigned short Wh1c[WSL][264], Wth1c[WSL][264], Wx1c[WSL][264];
  __shared__ __align__(16) unsigned short Whh0c[24][264], Whh1c[24][264], Wih1c[24][264];
  __shared__ float bh0s[8], bth0s[8], bh1s[8], bth1s[8], bx1s[8];
  __shared__ float bhh0s[24], bhh1s[24], bih1s[24];
  // per-step scratch (single batch)
  __shared__ __align__(16) float nh0_s[260], li1_s[260];
  __shared__ __align__(16) float sm_s[2][260];               // rows: L0, L1
  __shared__ float xps0_s[8], xps1a_s[8], xps1b_s[8];
  __shared__ float gi1_s[24], gh0_s[24], gh1_s[24];
  __shared__ float agg0_s[8], agg1_s[8], redsum_s[2][2];
  __shared__ float gipre_s[3][8];
  __shared__ float v0s[8], v1s[8];

  const int bid = blockIdx.x, tid = threadIdx.x;
  const int grp = bid >> 5;          // 0..3 == batch index
  const int bidg = bid & 31;         // block within group
  const int c0 = bidg * WSL;         // first owned column
  const int gb = grp;                // batch
  unsigned long long* S0 = s0buf + grp * 384;   // [3 parity][128 pr]
  unsigned long long* S1 = s1buf + grp * 384;

  // ---- load weight slices (one-time) ----
  for (int idx = tid; idx < WSL * kH; idx += NTHR) {
    int c = idx >> 8, h = idx & 255, col = c0 + c;
    Wh0c[c][h]  = f2bfu(Wh0[h * kA + col]);
    Wth0c[c][h] = f2bfu(Wth0[h * kA + col]);
    Wh1c[c][h]  = f2bfu(Wh1[h * kA + col]);
    Wth1c[c][h] = f2bfu(Wth1[h * kA + col]);
    Wx1c[c][h]  = f2bfu(Wx1[h * kA + col]);
  }
  for (int idx = tid; idx < 24 * kH; idx += NTHR) {
    int cc = idx >> 8, h = idx & 255;
    int n = (cc >> 3) * kH + c0 + (cc & 7);
    Whh0c[cc][h] = f2bfu(Whh0[h * 768 + n]);
    Whh1c[cc][h] = f2bfu(Whh1[h * 768 + n]);
    Wih1c[cc][h] = f2bfu(Wih1[h * 768 + n]);
  }
  if (tid < 8) {
    int c = c0 + tid;
    bh0s[tid] = bh0[c]; bth0s[tid] = bth0[c];
    bh1s[tid] = bh1[c]; bth1s[tid] = bth1[c]; bx1s[tid] = bx1[c];
    v0s[tid] = v0[c]; v1s[tid] = v1[c];
  }
  if (tid < 24) {
    int n = (tid >> 3) * kH + c0 + (tid & 7);
    bhh0s[tid] = bhh0[n]; bhh1s[tid] = bhh1[n]; bih1s[tid] = bih1[n];
  }
  __syncthreads();

  // ---- prologue: nh0(0) (t=0: agg=h=0, gh=bhh) ----
  if (tid < 8) {
    int c = tid, hcol = c0 + c;
    const float* gi = gi0_all + (size_t)(gb * kT) * 768;
    float r = f_sig(gi[hcol] + bhh0s[c]);
    float u = f_sig(gi[256 + hcol] + bhh0s[8 + c]);
    float n = f_tanh(gi[512 + hcol] + r * bhh0s[16 + c]);
    float val = (1.f - u) * n;
    tape0_s[0][c] = f2bfu(val);
    float other = __shfl_xor(val, 1);   // partner col c^1
    if ((c & 1) == 0) {
      unsigned long long pk = (unsigned long long)f2u(val) |
                              ((unsigned long long)f2u(other) << 32);
      astore64(&nh0p[(size_t)(gb * kT) * 128 + bidg * 4 + (c >> 1)], pk);
    }
  }

  const float SCL = 65536.f;                  // fixed-point scale 2^16
  const float fxi = 1.44269504f / 65536.f;    // log2(e)/2^16

  for (int k = 0; k < kT; ++k) {
    // ======= phase A: poll nh0(k) (tid<128) OVERLAPPED with the 40
    // L1-recurrent dots (tid 128..287) reading nh1(k-1) from global =========
    if (tid < 128) {
      int pr = tid, h = pr * 2;
      const unsigned long long* p = &nh0p[(size_t)(gb * kT + k) * 128 + pr];
      unsigned long long v = aload64(p);
      int it = 0;
      while (v == CANARY) {
        v = aload64(p);
        if (++it > (1 << 24)) break;   // fail loud, not hang
      }
      float lo = u2f((unsigned int)v), hi = u2f((unsigned int)(v >> 32));
      nh0_s[h] = lo; nh0_s[h + 1] = hi;
      float2 ce2 = *(const float2*)&ce_all[(size_t)(gb * kT + k) * 256 + h];
      li1_s[h]     = fmaxf(lo + ce2.x, 0.f);
      li1_s[h + 1] = fmaxf(hi + ce2.y, 0.f);
    } else if (tid < 288) {
      if (k > 0) {
        int p = (tid - 128) >> 2, q = tid & 3;
        const unsigned long long* xrow = &nh1p[(size_t)(gb * kT + k - 1) * 128];
        if (p < 8) {                  // hw1 (+bth)
          float acc = dot_nh1g(xrow, Wth1c[p], q);
          acc += __shfl_xor(acc, 1); acc += __shfl_xor(acc, 2);
          if (q == 0) xps1b_s[p] = acc + bth1s[p];
        } else if (p < 16) {          // tape@Wh1 row k-1 (+bh)
          int c = p - 8;
          float acc = dot_nh1g(xrow, Wh1c[c], q);
          acc += __shfl_xor(acc, 1); acc += __shfl_xor(acc, 2);
          if (q == 0) tWh1_s[k - 1][c] = f2bfu(acc + bh1s[c]);
        } else {                      // tape@Whh1 row k-1
          int cc = p - 16;
          float acc = dot_nh1g(xrow, Whh1c[cc], q);
          acc += __shfl_xor(acc, 1); acc += __shfl_xor(acc, 2);
          if (q == 0) tWhh1_s[k - 1][cc] = f2bfu(acc);
        }
      }
    } else if (tid < 296) {
      if (k < kT - 1) {               // prefetch gi0 row k+1
        int c = tid - 288, hcol = c0 + c;
        const float* gi = gi0_all + (size_t)(gb * kT + k + 1) * 768;
        gipre_s[0][c] = gi[hcol];
        gipre_s[1][c] = gi[256 + hcol];
        gipre_s[2][c] = gi[512 + hcol];
      }
    }
    // zero score slots of parity (k+1)%3 (used at step k+1; last read step k-2)
    if (tid >= NTHR - 8) {
      int z = tid - (NTHR - 8);
      int pz = (k + 1) % 3;
      int idx = bidg * 4 + (z & 3);     // 32 blocks x 4 = 128 slots
      if (z < 4) astore64(&S0[pz * 128 + idx], 0ull);
      else       astore64(&S1[pz * 128 + idx], 0ull);
    }
    __syncthreads();

    {   // remaining 72 GEMVs (288 threads, strided quarters, LDS inputs)
      int p = tid >> 2, q = tid & 3;
      if (p < 40) {
        if (k < kT - 1) {
          if (p < 8) {                // hw0 (+bth) + xw0 -> xps0
            int c = p;
            float acc = dot_bf64s(nh0_s, Wth0c[c], q);
            acc += __shfl_xor(acc, 1); acc += __shfl_xor(acc, 2);
            if (q == 0) {
              float xw = xw0_all[(size_t)(gb * kT + k + 1) * kA + c0 + c];
              xps0_s[c] = acc + bth0s[c] + xw;
            }
          } else if (p < 16) {        // tape@Wh0 row k (own cols, +bh)
            int c = p - 8;
            float acc = dot_bf64s(nh0_s, Wh0c[c], q);
            acc += __shfl_xor(acc, 1); acc += __shfl_xor(acc, 2);
            if (q == 0) tWh0_s[k][c] = f2bfu(acc + bh0s[c]);
          } else {                    // tape@Whh0 row k
            int cc = p - 16;
            float acc = dot_bf64s(nh0_s, Whh0c[cc], q);
            acc += __shfl_xor(acc, 1); acc += __shfl_xor(acc, 2);
            if (q == 0) tWhh0_s[k][cc] = f2bfu(acc);
          }
        }
      } else if (p < 64) {            // gi1 = li1@Wih1 (+bih)
        int cc = p - 40;
        float acc = dot_bf64s(li1_s, Wih1c[cc], q);
        acc += __shfl_xor(acc, 1); acc += __shfl_xor(acc, 2);
        if (q == 0) gi1_s[cc] = acc + bih1s[cc];
      } else if (p < 72) {            // xw1 = li1@Wx1 (+bx)
        int c = p - 64;
        float acc = dot_bf64s(li1_s, Wx1c[c], q);
        acc += __shfl_xor(acc, 1); acc += __shfl_xor(acc, 2);
        if (q == 0) xps1a_s[c] = acc + bx1s[c];
      }
    }
    __syncthreads();

    {   // partial scores over own 8 a-cols; count-embedded u64 atomic reduce
      int cnt0w = k + 1, cnt1w = k;
      int np0 = (k < kT - 1) ? ((cnt0w + 1) >> 1) : 0;   // j-pairs, <=128
      int np1 = (cnt1w + 1) >> 1;
      int pk = k % 3;
      unsigned long long* d0 = S0 + pk * 128;
      unsigned long long* d1 = S1 + pk * 128;
      for (int pp = tid; pp < np0 + np1; pp += NTHR) {
        float p0, p1; unsigned long long* dst;
        if (pp < np0) {
          int j0 = 2 * pp;
          p0 = sc4(&tWh0_s[j0][0], xps0_s, v0s) + sc4(&tWh0_s[j0][4], xps0_s + 4, v0s + 4);
          p1 = 0.f;
          if (j0 + 1 < cnt0w)
            p1 = sc4(&tWh0_s[j0 + 1][0], xps0_s, v0s) + sc4(&tWh0_s[j0 + 1][4], xps0_s + 4, v0s + 4);
          dst = d0 + pp;
        } else {
          int pr = pp - np0, j0 = 2 * pr;
          float xp[8];
#pragma unroll
          for (int c = 0; c < 8; ++c) xp[c] = xps1a_s[c] + xps1b_s[c];
          p0 = sc4(&tWh1_s[j0][0], xp, v1s) + sc4(&tWh1_s[j0][4], xp + 4, v1s + 4);
          p1 = 0.f;
          if (j0 + 1 < cnt1w)
            p1 = sc4(&tWh1_s[j0 + 1][0], xp, v1s) + sc4(&tWh1_s[j0 + 1][4], xp + 4, v1s + 4);
          dst = d1 + pr;
        }
        int q0 = (int)rintf(p0 * SCL) + SBIAS;
        int q1 = (int)rintf(p1 * SCL) + SBIAS;
        unsigned long long add = (unsigned long long)(unsigned int)q0 |
                                 ((unsigned long long)(unsigned int)q1 << 32);
        __hip_atomic_fetch_add(dst, add, __ATOMIC_RELAXED, __HIP_MEMORY_SCOPE_AGENT);
      }
    }
    __syncthreads();   // park fast waves until all atomics are issued

    // ================= phase B (dataflow — 128 lanes per softmax row) =======
    int cnt0 = (k < kT - 1) ? (k + 1) : 0;
    int cnt1 = k;
    if (tid < 256) {   // exp(score) + per-row sum; each lane owns one u64 slot
      int r = tid >> 7, lane = tid & 127;
      float sum = 0.f;
      int cnt = (r == 0) ? cnt0 : cnt1;
      if (cnt) {
        int pk = k % 3;
        const unsigned long long* sb = (r == 0) ? S0 + pk * 128 : S1 + pk * 128;
        int npr = (cnt + 1) >> 1;    // <= 128
        if (lane < npr) {
          unsigned long long v = aload64(&sb[lane]);
          int it = 0;
          while (!sready(v)) {
            v = aload64(&sb[lane]);
            if (++it > (1 << 24)) break;   // fail loud, not hang
          }
          int lo = (int)(unsigned int)(v & 0xffffffffull) - SBIAS_TOT;
          int hi = (int)(unsigned int)(v >> 32) - SBIAS_TOT;
          float e0 = fexp2((float)lo * fxi);
          sm_s[r][2 * lane] = e0; sum += e0;
          if (2 * lane + 1 < cnt) {
            float e1 = fexp2((float)hi * fxi);
            sm_s[r][2 * lane + 1] = e1; sum += e1;
          }
        }
      }
      for (int m = 32; m >= 1; m >>= 1) sum += __shfl_xor(sum, m);
      if ((tid & 63) == 0) redsum_s[r][(tid >> 6) & 1] = sum;
    }
    __syncthreads();

    {   // fused gh (=sum w*tapeWhh) and agg (=sum w*tape), own cols; 8 subs
      int slot = tid >> 3, sub = tid & 7;
      float accA = 0.f, accB = 0.f;
      if (slot < 24) {
        if (cnt0) {
          int cc = slot;
#pragma unroll 4
          for (int j = sub; j < cnt0; j += 16) accA += sm_s[0][j] * bfu2f(tWhh0_s[j][cc]);
#pragma unroll 4
          for (int j = sub + 8; j < cnt0; j += 16) accB += sm_s[0][j] * bfu2f(tWhh0_s[j][cc]);
          float acc = accA + accB;
          acc += __shfl_xor(acc, 1); acc += __shfl_xor(acc, 2); acc += __shfl_xor(acc, 4);
          if (sub == 0) gh0_s[cc] = acc * frcp(redsum_s[0][0] + redsum_s[0][1]) + bhh0s[cc];
        }
      } else if (slot < 32) {
        if (cnt0) {
          int c = slot - 24;
#pragma unroll 4
          for (int j = sub; j < cnt0; j += 16) accA += sm_s[0][j] * bfu2f(tape0_s[j][c]);
#pragma unroll 4
          for (int j = sub + 8; j < cnt0; j += 16) accB += sm_s[0][j] * bfu2f(tape0_s[j][c]);
          float acc = accA + accB;
          acc += __shfl_xor(acc, 1); acc += __shfl_xor(acc, 2); acc += __shfl_xor(acc, 4);
          if (sub == 0) agg0_s[c] = acc * frcp(redsum_s[0][0] + redsum_s[0][1]);
        }
      } else if (slot < 56) {
        if (cnt1) {
          int cc = slot - 32;
#pragma unroll 4
          for (int j = sub; j < cnt1; j += 16) accA += sm_s[1][j] * bfu2f(tWhh1_s[j][cc]);
#pragma unroll 4
          for (int j = sub + 8; j < cnt1; j += 16) accB += sm_s[1][j] * bfu2f(tWhh1_s[j][cc]);
          float acc = accA + accB;
          acc += __shfl_xor(acc, 1); acc += __shfl_xor(acc, 2); acc += __shfl_xor(acc, 4);
          if (sub == 0) gh1_s[cc] = acc * frcp(redsum_s[1][0] + redsum_s[1][1]) + bhh1s[cc];
        }
      } else if (slot < 64) {
        if (cnt1) {
          int c = slot - 56;
#pragma unroll 4
          for (int j = sub; j < cnt1; j += 16) accA += sm_s[1][j] * bfu2f(tape1_s[j][c]);
#pragma unroll 4
          for (int j = sub + 8; j < cnt1; j += 16) accB += sm_s[1][j] * bfu2f(tape1_s[j][c]);
          float acc = accA + accB;
          acc += __shfl_xor(acc, 1); acc += __shfl_xor(acc, 2); acc += __shfl_xor(acc, 4);
          if (sub == 0) agg1_s[c] = acc * frcp(redsum_s[1][0] + redsum_s[1][1]);
        }
      }
    }
    __syncthreads();

    // GRU updates (two waves in parallel); publish packed nh pairs
    if (tid < 8) {             // L0 -> nh0(k+1)
      if (k < kT - 1) {
        int c = tid, hcol = c0 + c, t0 = k + 1;
        float agg = agg0_s[c];
        float r = f_sig(gipre_s[0][c] + gh0_s[c]);
        float u = f_sig(gipre_s[1][c] + gh0_s[8 + c]);
        float n = f_tanh(gipre_s[2][c] + r * gh0_s[16 + c]);
        float val = (1.f - u) * n + u * agg;
        tape0_s[t0][c] = f2bfu(val);
        if (t0 == kT - 1) out_tail[gb * kH + hcol] = val;     // h0 final
        float other = __shfl_xor(val, 1);
        if ((c & 1) == 0) {
          unsigned long long pk = (unsigned long long)f2u(val) |
                                  ((unsigned long long)f2u(other) << 32);
          astore64(&nh0p[(size_t)(gb * kT + t0) * 128 + bidg * 4 + (c >> 1)], pk);
        }
      }
    } else if (tid >= 64 && tid < 72) {   // L1 -> nh1(k)
      int c = tid - 64, hcol = c0 + c;
      float ghr, ghu, ghn, agg;
      if (k > 0) { ghr = gh1_s[c]; ghu = gh1_s[8 + c]; ghn = gh1_s[16 + c]; agg = agg1_s[c]; }
      else       { ghr = bhh1s[c]; ghu = bhh1s[8 + c]; ghn = bhh1s[16 + c]; agg = 0.f; }
      float r = f_sig(gi1_s[c] + ghr);
      float u = f_sig(gi1_s[8 + c] + ghu);
      float n = f_tanh(gi1_s[16 + c] + r * ghn);
      float val = (1.f - u) * n + u * agg;
      tape1_s[k][c] = f2bfu(val);
      cat1_all[(size_t)(gb * kT + k) * 512 + hcol] = val;
      if (k == kT - 1) out_tail[kB * kH + gb * kH + hcol] = val;   // h1 final
      float other = __shfl_xor(val, 1);
      if ((c & 1) == 0) {
        unsigned long long pk = (unsigned long long)f2u(val) |
                                ((unsigned long long)f2u(other) << 32);
        astore64(&nh1p[(size_t)(gb * kT + k) * 128 + bidg * 4 + (c >> 1)], pk);
      }
    }
    // no loop-end __syncthreads: next phase A writes disjoint LDS arrays and
    // its own __syncthreads orders them before any cross-phase reads.
  }
}

// ---------------- launch -----------------------------------------------------
extern "C" void kernel_launch(void* const* d_in, const int* in_sizes, int n_in,
                              void* d_out, int out_size, void* d_ws, size_t ws_size,
                              hipStream_t stream) {
  const int*   input_ids    = (const int*)d_in[0];
  const int*   category_ids = (const int*)d_in[1];
  const float* emb     = (const float*)d_in[2];
  const float* cat_emb = (const float*)d_in[3];
  const float* Wih0 = (const float*)d_in[4];
  const float* bih0 = (const float*)d_in[5];
  const float* Whh0 = (const float*)d_in[6];  const float* bhh0 = (const float*)d_in[7];
  const float* Wh0  = (const float*)d_in[8];  const float* bh0  = (const float*)d_in[9];
  const float* Wx0  = (const float*)d_in[10]; const float* bx0  = (const float*)d_in[11];
  const float* Wth0 = (const float*)d_in[12]; const float* bth0 = (const float*)d_in[13];
  const float* v0   = (const float*)d_in[14];
  const float* Wih1 = (const float*)d_in[16]; const float* bih1 = (const float*)d_in[17];
  const float* Whh1 = (const float*)d_in[18]; const float* bhh1 = (const float*)d_in[19];
  const float* Wh1  = (const float*)d_in[20]; const float* bh1  = (const float*)d_in[21];
  const float* Wx1  = (const float*)d_in[22]; const float* bx1  = (const float*)d_in[23];
  const float* Wth1 = (const float*)d_in[24]; const float* bth1 = (const float*)d_in[25];
  const float* v1   = (const float*)d_in[26];
  const float* Wctx = (const float*)d_in[28]; const float* bctx = (const float*)d_in[29];
  const float* Wout = (const float*)d_in[30]; const float* bout = (const float*)d_in[31];

  float* ws = (float*)d_ws;
  float* li0_all  = ws;                    // [1024][512] region (score bufs overlay)
  float* ce_all   = li0_all + 524288;      // [1024][256]
  float* gi0_all  = ce_all + 262144;       // [1024][768]
  float* xw0_all  = gi0_all + 786432;      // [1024][256]
  unsigned long long* nh0p = (unsigned long long*)(xw0_all + 262144);  // [B*T][128] u64
  unsigned long long* nh1p = nh0p + 131072;                            // [B*T][128] u64
  float* cat1_all = (float*)(nh1p + 131072);   // [1024][512]
  unsigned short* ctx_bf = (unsigned short*)(cat1_all + 524288);  // [1024][512] bf16
  unsigned short* li0bf  = ctx_bf + 524288;                       // [1024][512] bf16

  // per-group score buffers OVERLAY the li0_all region (unused otherwise)
  unsigned long long* s0buf = (unsigned long long*)li0_all;  // [4 grp][3 par][128]
  unsigned long long* s1buf = s0buf + 1536;                  // same
  int    nzero_s  = 2 * 1536 * 2;          // scores, in ints
  int    nfill_nh = 2 * 131072 * 2;        // nh0p+nh1p, in ints

  float* out = (float*)d_out;
  float* out_tail = out + (size_t)kB * kT * kV;

  embed_kernel<<<dim3(kB * kT), dim3(256), 0, stream>>>(input_ids, category_ids, emb, cat_emb,
                                                        li0bf, ce_all, cat1_all);
  gemm_mfma_f32out<<<dim3(12, 16), dim3(256), 0, stream>>>(li0bf, Wih0, bih0, gi0_all, 768);
  gemm_mfma_f32out<<<dim3(4, 16), dim3(256), 0, stream>>>(li0bf, Wx0, bx0, xw0_all, 256);
  init_kernel<<<dim3(8), dim3(512), 0, stream>>>((int*)s0buf, nzero_s, 0);
  init_kernel<<<dim3(128), dim3(512), 0, stream>>>((int*)nh0p, nfill_nh, -1);       // NaN canary
  coop_kernel<<<dim3(NBLKS), dim3(NTHR), 0, stream>>>(gi0_all, xw0_all, ce_all, nh0p, nh1p,
      cat1_all, out_tail, s0buf, s1buf,
      Whh0, bhh0, Wh0, bh0, Wth0, bth0, v0,
      Wih1, bih1, Whh1, bhh1, Wh1, bh1, Wx1, bx1, Wth1, bth1, v1);
  gemm_ctx_bf16<<<dim3(8, 16), dim3(256), 0, stream>>>(cat1_all, Wctx, bctx, ctx_bf);
  gemm_logits_mfma<<<dim3(500), dim3(256), 0, stream>>>(ctx_bf, Wout, bout, out);
}

// Round 24
// 1990.391 us; speedup vs baseline: 2.2467x; 2.2467x over previous
//
#include <hip/hip_runtime.h>

#define DEVINL __device__ __forceinline__

// Problem constants
constexpr int kB = 4, kT = 256, kH = 256, kA = 256, kV = 32000;
constexpr int NBLKS = 128;  // 4 groups x 32 blocks (one batch per group)
constexpr int NGRP = 32;    // blocks per group == contributors per score slot
constexpr int NTHR = 512;   // 8 waves per block
constexpr int WSL = 8;      // column-slice width = 256 / 32
constexpr int SBIAS = 1 << 24;             // per-contribution bias == arrival count unit
constexpr int SBIAS_TOT = NGRP * SBIAS;    // 2^29, subtract at read
constexpr unsigned long long CANARY = ~0ull;  // NaN|NaN — unreachable by finite nh pairs

typedef __attribute__((ext_vector_type(8))) short bf16x8;
typedef __attribute__((ext_vector_type(4))) float f32x4;

// ---------------- fast math helpers -----------------------------------------
DEVINL float fexp2(float x) { float y; asm("v_exp_f32 %0, %1" : "=v"(y) : "v"(x)); return y; }
DEVINL float frcp(float x)  { float y; asm("v_rcp_f32 %0, %1" : "=v"(y) : "v"(x)); return y; }
DEVINL float f_tanh(float x) {
  float t = fexp2(x * 2.88539008f);           // e^{2x}
  return 1.f - 2.f * frcp(t + 1.f);
}
DEVINL float f_sig(float x) { return frcp(1.f + fexp2(-x * 1.44269504f)); }

DEVINL float bfu2f(unsigned short u) {
  union { unsigned int i; float f; } c; c.i = ((unsigned int)u) << 16; return c.f;
}
DEVINL unsigned short f2bfu(float f) {
  union { float f; unsigned int i; } c; c.f = f;
  unsigned int r = c.i + 0x7fffu + ((c.i >> 16) & 1u);   // RNE
  return (unsigned short)(r >> 16);
}
DEVINL unsigned int f2u(float f) { union { float f; unsigned int i; } c; c.f = f; return c.i; }
DEVINL float u2f(unsigned int u) { union { unsigned int i; float f; } c; c.i = u; return c.f; }

// coherent (agent-scope, memory-side) access helpers — all RELAXED
DEVINL unsigned long long aload64(const unsigned long long* p) {
  return __hip_atomic_load(p, __ATOMIC_RELAXED, __HIP_MEMORY_SCOPE_AGENT);
}
DEVINL void astore64(unsigned long long* p, unsigned long long v) {
  __hip_atomic_store(p, v, __ATOMIC_RELAXED, __HIP_MEMORY_SCOPE_AGENT);
}

// score slot readiness: each 32-bit field carries count*2^24 + val (|val|<2^23)
DEVINL bool sready(unsigned long long v) {
  unsigned int lo = (unsigned int)v, hi = (unsigned int)(v >> 32);
  return (((lo + (1u << 23)) >> 24) == (unsigned)NGRP) &&
         (((hi + (1u << 23)) >> 24) == (unsigned)NGRP);
}

// STRIDED quarter-dot: quarter q processes ushort4-chunks q, q+4, ..., q+60.
// Chunk offset q*8B = 2 banks -> the 4 quarters hit DISTINCT banks.
DEVINL float dot_bf64s(const float* x, const unsigned short* w, int q) {
  float a0 = 0.f, a1 = 0.f, a2 = 0.f, a3 = 0.f;
  const float4*  x4 = (const float4*)x;
  const ushort4* w4 = (const ushort4*)w;
#pragma unroll
  for (int i = 0; i < 16; ++i) {
    int c = q + 4 * i;
    float4 xv = x4[c]; ushort4 wv = w4[c];
    a0 += xv.x * bfu2f(wv.x);
    a1 += xv.y * bfu2f(wv.y);
    a2 += xv.z * bfu2f(wv.z);
    a3 += xv.w * bfu2f(wv.w);
  }
  return (a0 + a1) + (a2 + a3);
}

// 4-term tanh score partial, 2 accumulators
DEVINL float sc4(const unsigned short* p4p, const float* xp, const float* vr) {
  ushort4 p4 = *(const ushort4*)p4p;
  float accA, accB;
  accA  = f_tanh(bfu2f(p4.x) + xp[0]) * vr[0];
  accB  = f_tanh(bfu2f(p4.y) + xp[1]) * vr[1];
  accA += f_tanh(bfu2f(p4.z) + xp[2]) * vr[2];
  accB += f_tanh(bfu2f(p4.w) + xp[3]) * vr[3];
  return accA + accB;
}

// ---------------- small kernels ----------------------------------------------
__global__ void init_kernel(int* dst, int nz, int val) {
  for (int i = blockIdx.x * blockDim.x + threadIdx.x; i < nz; i += gridDim.x * blockDim.x)
    dst[i] = val;
}

__global__ void embed_kernel(const int* __restrict__ ids, const int* __restrict__ cids,
                             const float* __restrict__ emb, const float* __restrict__ cat_emb,
                             unsigned short* __restrict__ li0bf, float* __restrict__ ce_all,
                             float* __restrict__ cat1_all) {
  int bt = blockIdx.x, e = threadIdx.x;
  int id = ids[bt], cid = cids[bt];
  float we = emb[id * kH + e];
  float ce = cat_emb[cid * kH + e];
  li0bf[bt * 512 + e]       = f2bfu(fmaxf(we + ce, 0.f));
  li0bf[bt * 512 + 256 + e] = f2bfu(fmaxf(ce + ce, 0.f));
  ce_all[bt * 256 + e] = ce;
  cat1_all[bt * 512 + 256 + e] = ce;   // upper half of [nh1, ce] concat
}

// ---------------- MFMA GEMM: C = A_bf16[1024,512] @ W[512,N] + bias (f32 out)
// One 64x64 tile per block; W panel staged f32->bf16 in LDS.
__global__ __launch_bounds__(256) void gemm_mfma_f32out(
    const unsigned short* __restrict__ A,    // [1024][512] bf16
    const float* __restrict__ Wm,            // [512][N] f32
    const float* __restrict__ bias,          // [N]
    float* __restrict__ C, int N) {          // [1024][N]
  __shared__ __align__(16) unsigned short Bt[64][520];
  const int tid = threadIdx.x;
  const int n0 = blockIdx.x * 64, m0 = blockIdx.y * 64;

  for (int idx = tid; idx < 512 * 16; idx += 256) {
    int k = idx >> 4, nq = (idx & 15) << 2;
    float4 v = *(const float4*)(Wm + (size_t)k * N + n0 + nq);
    Bt[nq + 0][k] = f2bfu(v.x); Bt[nq + 1][k] = f2bfu(v.y);
    Bt[nq + 2][k] = f2bfu(v.z); Bt[nq + 3][k] = f2bfu(v.w);
  }
  __syncthreads();

  const int l = tid & 63, w = tid >> 6;
  const int lrow = l & 15, lk = (l >> 4) * 8;
  float bia0 = bias[n0 +  0 + lrow];
  float bia1 = bias[n0 + 16 + lrow];
  float bia2 = bias[n0 + 32 + lrow];
  float bia3 = bias[n0 + 48 + lrow];

  f32x4 acc0 = {0.f, 0.f, 0.f, 0.f}, acc1 = acc0, acc2 = acc0, acc3 = acc0;
  const unsigned short* Arow = A + (size_t)(m0 + w * 16 + lrow) * 512 + lk;
#pragma unroll
  for (int ks = 0; ks < 16; ++ks) {
    bf16x8 a  = *(const bf16x8*)(Arow + ks * 32);
    bf16x8 b0 = *(const bf16x8*)&Bt[ 0 + lrow][ks * 32 + lk];
    bf16x8 b1 = *(const bf16x8*)&Bt[16 + lrow][ks * 32 + lk];
    bf16x8 b2 = *(const bf16x8*)&Bt[32 + lrow][ks * 32 + lk];
    bf16x8 b3 = *(const bf16x8*)&Bt[48 + lrow][ks * 32 + lk];
    acc0 = __builtin_amdgcn_mfma_f32_16x16x32_bf16(a, b0, acc0, 0, 0, 0);
    acc1 = __builtin_amdgcn_mfma_f32_16x16x32_bf16(a, b1, acc1, 0, 0, 0);
    acc2 = __builtin_amdgcn_mfma_f32_16x16x32_bf16(a, b2, acc2, 0, 0, 0);
    acc3 = __builtin_amdgcn_mfma_f32_16x16x32_bf16(a, b3, acc3, 0, 0, 0);
  }
  int orow = m0 + w * 16 + (l >> 4) * 4;
#pragma unroll
  for (int r = 0; r < 4; ++r) {
    float* Cr = C + (size_t)(orow + r) * N + n0;
    Cr[ 0 + lrow] = acc0[r] + bia0;
    Cr[16 + lrow] = acc1[r] + bia1;
    Cr[32 + lrow] = acc2[r] + bia2;
    Cr[48 + lrow] = acc3[r] + bia3;
  }
}

// ---------------- ctx GEMM: ctx_bf = bf16(tanh(cat1 @ Wctx + bctx)) ----------
__global__ __launch_bounds__(256) void gemm_ctx_bf16(const float* __restrict__ A,
                                                     const float* __restrict__ Wm,
                                                     const float* __restrict__ bias,
                                                     unsigned short* __restrict__ Cb) {
  const int N = 500, K = 512;
  __shared__ __align__(16) float As[16][68];
  __shared__ __align__(16) float Bs[16][68];
  int tid = threadIdx.x;
  int tx = tid & 15, ty = tid >> 4;
  int row0 = blockIdx.y * 64, col0 = blockIdx.x * 64;
  int ar = tid >> 2;
  int ak = (tid & 3) * 4;
  int br = tid >> 4;
  int bc = (tid & 15) * 4;
  float acc[4][4] = {};
  for (int k0 = 0; k0 < K; k0 += 16) {
    float4 av = *(const float4*)(A + (size_t)(row0 + ar) * K + k0 + ak);
    As[ak + 0][ar] = av.x; As[ak + 1][ar] = av.y; As[ak + 2][ar] = av.z; As[ak + 3][ar] = av.w;
    float4 bv = {0.f, 0.f, 0.f, 0.f};
    int wrow = k0 + br;
    if (col0 + bc + 3 < N) bv = *(const float4*)(Wm + (size_t)wrow * N + col0 + bc);
    else {
      float t[4] = {0.f, 0.f, 0.f, 0.f};
      for (int u = 0; u < 4; ++u) if (col0 + bc + u < N) t[u] = Wm[(size_t)wrow * N + col0 + bc + u];
      bv.x = t[0]; bv.y = t[1]; bv.z = t[2]; bv.w = t[3];
    }
    *(float4*)&Bs[br][bc] = bv;
    __syncthreads();
#pragma unroll
    for (int kk = 0; kk < 16; ++kk) {
      float4 a4 = *(const float4*)&As[kk][ty * 4];
      float4 b4 = *(const float4*)&Bs[kk][tx * 4];
      acc[0][0] += a4.x * b4.x; acc[0][1] += a4.x * b4.y; acc[0][2] += a4.x * b4.z; acc[0][3] += a4.x * b4.w;
      acc[1][0] += a4.y * b4.x; acc[1][1] += a4.y * b4.y; acc[1][2] += a4.y * b4.z; acc[1][3] += a4.y * b4.w;
      acc[2][0] += a4.z * b4.x; acc[2][1] += a4.z * b4.y; acc[2][2] += a4.z * b4.z; acc[2][3] += a4.z * b4.w;
      acc[3][0] += a4.w * b4.x; acc[3][1] += a4.w * b4.y; acc[3][2] += a4.w * b4.z; acc[3][3] += a4.w * b4.w;
    }
    __syncthreads();
  }
#pragma unroll
  for (int i = 0; i < 4; ++i) {
    int r = row0 + ty * 4 + i;
#pragma unroll
    for (int j = 0; j < 4; ++j) {
      int c = col0 + tx * 4 + j;
      if (c < N) {
        float v = f_tanh(acc[i][j] + bias[c]);
        Cb[(size_t)r * 512 + c] = f2bfu(v);
      } else {
        Cb[(size_t)r * 512 + c] = 0;
      }
    }
  }
}

// ---------------- logits GEMM via MFMA bf16 ----------------------------------
__global__ __launch_bounds__(256) void gemm_logits_mfma(
    const unsigned short* __restrict__ A,    // ctx_bf [1024][512] bf16 (K-padded)
    const float* __restrict__ Wout,          // [500][32000] f32
    const float* __restrict__ bout,          // [32000]
    float* __restrict__ C) {                 // [1024][32000]
  __shared__ __align__(16) unsigned short Bt[64][520];
  const int tid = threadIdx.x;
  const int n0 = blockIdx.x * 64;

  for (int idx = tid; idx < 512 * 16; idx += 256) {
    int k = idx >> 4, nq = (idx & 15) << 2;
    if (k < 500) {
      float4 v = *(const float4*)(Wout + (size_t)k * 32000 + n0 + nq);
      Bt[nq + 0][k] = f2bfu(v.x); Bt[nq + 1][k] = f2bfu(v.y);
      Bt[nq + 2][k] = f2bfu(v.z); Bt[nq + 3][k] = f2bfu(v.w);
    } else {
      Bt[nq + 0][k] = 0; Bt[nq + 1][k] = 0; Bt[nq + 2][k] = 0; Bt[nq + 3][k] = 0;
    }
  }
  __syncthreads();

  const int l = tid & 63, w = tid >> 6;
  const int lrow = l & 15, lk = (l >> 4) * 8;
  float bia0 = bout[n0 +  0 + lrow];
  float bia1 = bout[n0 + 16 + lrow];
  float bia2 = bout[n0 + 32 + lrow];
  float bia3 = bout[n0 + 48 + lrow];

  for (int m0 = 0; m0 < 1024; m0 += 64) {
    f32x4 acc0 = {0.f, 0.f, 0.f, 0.f}, acc1 = acc0, acc2 = acc0, acc3 = acc0;
    const unsigned short* Arow = A + (size_t)(m0 + w * 16 + lrow) * 512 + lk;
#pragma unroll
    for (int ks = 0; ks < 16; ++ks) {
      bf16x8 a  = *(const bf16x8*)(Arow + ks * 32);
      bf16x8 b0 = *(const bf16x8*)&Bt[ 0 + lrow][ks * 32 + lk];
      bf16x8 b1 = *(const bf16x8*)&Bt[16 + lrow][ks * 32 + lk];
      bf16x8 b2 = *(const bf16x8*)&Bt[32 + lrow][ks * 32 + lk];
      bf16x8 b3 = *(const bf16x8*)&Bt[48 + lrow][ks * 32 + lk];
      acc0 = __builtin_amdgcn_mfma_f32_16x16x32_bf16(a, b0, acc0, 0, 0, 0);
      acc1 = __builtin_amdgcn_mfma_f32_16x16x32_bf16(a, b1, acc1, 0, 0, 0);
      acc2 = __builtin_amdgcn_mfma_f32_16x16x32_bf16(a, b2, acc2, 0, 0, 0);
      acc3 = __builtin_amdgcn_mfma_f32_16x16x32_bf16(a, b3, acc3, 0, 0, 0);
    }
    int orow = m0 + w * 16 + (l >> 4) * 4;
#pragma unroll
    for (int r = 0; r < 4; ++r) {
      float* Cr = C + (size_t)(orow + r) * 32000 + n0;
      Cr[ 0 + lrow] = acc0[r] + bia0;
      Cr[16 + lrow] = acc1[r] + bia1;
      Cr[32 + lrow] = acc2[r] + bia2;
      Cr[48 + lrow] = acc3[r] + bia3;
    }
  }
}

// ---------------- persistent cooperative recurrence kernel -------------------
// FULL DATAFLOW — zero grid barriers. 4 INDEPENDENT groups x 32 blocks, one
// BATCH per group. Block owns 8 a/h-cols. GEMVs split 4-way with STRIDED
// chunk assignment (bank-conflict-free). Score fan-in: count-embedded u64
// atomics, parity-3 rotation. nh broadcast: packed f32-pair + canary,
// SINGLE poll per thread into LDS (per-element global polling is 2.4x slower
// — round-23 lesson: agent-scope atomic loads always pay the LLC round trip).
__global__ __launch_bounds__(NTHR, 1) void coop_kernel(
    const float* __restrict__ gi0_all, const float* __restrict__ xw0_all,
    const float* __restrict__ ce_all,
    unsigned long long* __restrict__ nh0p, unsigned long long* __restrict__ nh1p,
    float* __restrict__ cat1_all, float* __restrict__ out_tail,
    unsigned long long* __restrict__ s0buf, unsigned long long* __restrict__ s1buf,
    const float* __restrict__ Whh0, const float* __restrict__ bhh0,
    const float* __restrict__ Wh0, const float* __restrict__ bh0,
    const float* __restrict__ Wth0, const float* __restrict__ bth0,
    const float* __restrict__ v0,
    const float* __restrict__ Wih1, const float* __restrict__ bih1,
    const float* __restrict__ Whh1, const float* __restrict__ bhh1,
    const float* __restrict__ Wh1, const float* __restrict__ bh1,
    const float* __restrict__ Wx1, const float* __restrict__ bx1,
    const float* __restrict__ Wth1, const float* __restrict__ bth1,
    const float* __restrict__ v1) {
  // ---- persistent LDS (~106 KB) ----
  __shared__ __align__(16) unsigned short tWhh0_s[kT][24];   // [j][cc] bf16
  __shared__ __align__(16) unsigned short tWhh1_s[kT][24];
  __shared__ __align__(16) unsigned short tape0_s[kT][8];    // [j][c] bf16
  __shared__ __align__(16) unsigned short tape1_s[kT][8];
  __shared__ __align__(16) unsigned short tWh0_s[kT][8];     // [j][c] bf16
  __shared__ __align__(16) unsigned short tWh1_s[kT][8];
  // weight column-slices (bf16, padded rows of 264)
  __shared__ __align__(16) unsigned short Wh0c[WSL][264], Wth0c[WSL][264];
  __shared__ __align__(16) unsigned short Wh1c[WSL][264], Wth1c[WSL][264], Wx1c[WSL][264];
  __shared__ __align__(16) unsigned short Whh0c[24][264], Whh1c[24][264], Wih1c[24][264];
  __shared__ float bh0s[8], bth0s[8], bh1s[8], bth1s[8], bx1s[8];
  __shared__ float bhh0s[24], bhh1s[24], bih1s[24];
  // per-step scratch (single batch)
  __shared__ __align__(16) float nh0_s[260], nh1_s[260], li1_s[260];
  __shared__ __align__(16) float sm_s[2][260];               // rows: L0, L1
  __shared__ float xps0_s[8], xps1a_s[8], xps1b_s[8];
  __shared__ float gi1_s[24], gh0_s[24], gh1_s[24];
  __shared__ float agg0_s[8], agg1_s[8], redsum_s[2][2];
  __shared__ float gipre_s[3][8];
  __shared__ float v0s[8], v1s[8];

  const int bid = blockIdx.x, tid = threadIdx.x;
  const int grp = bid >> 5;          // 0..3 == batch index
  const int bidg = bid & 31;         // block within group
  const int c0 = bidg * WSL;         // first owned column
  const int gb = grp;                // batch
  unsigned long long* S0 = s0buf + grp * 384;   // [3 parity][128 pr]
  unsigned long long* S1 = s1buf + grp * 384;

  // ---- load weight slices (one-time) ----
  for (int idx = tid; idx < WSL * kH; idx += NTHR) {
    int c = idx >> 8, h = idx & 255, col = c0 + c;
    Wh0c[c][h]  = f2bfu(Wh0[h * kA + col]);
    Wth0c[c][h] = f2bfu(Wth0[h * kA + col]);
    Wh1c[c][h]  = f2bfu(Wh1[h * kA + col]);
    Wth1c[c][h] = f2bfu(Wth1[h * kA + col]);
    Wx1c[c][h]  = f2bfu(Wx1[h * kA + col]);
  }
  for (int idx = tid; idx < 24 * kH; idx += NTHR) {
    int cc = idx >> 8, h = idx & 255;
    int n = (cc >> 3) * kH + c0 + (cc & 7);
    Whh0c[cc][h] = f2bfu(Whh0[h * 768 + n]);
    Whh1c[cc][h] = f2bfu(Whh1[h * 768 + n]);
    Wih1c[cc][h] = f2bfu(Wih1[h * 768 + n]);
  }
  if (tid < 8) {
    int c = c0 + tid;
    bh0s[tid] = bh0[c]; bth0s[tid] = bth0[c];
    bh1s[tid] = bh1[c]; bth1s[tid] = bth1[c]; bx1s[tid] = bx1[c];
    v0s[tid] = v0[c]; v1s[tid] = v1[c];
  }
  if (tid < 24) {
    int n = (tid >> 3) * kH + c0 + (tid & 7);
    bhh0s[tid] = bhh0[n]; bhh1s[tid] = bhh1[n]; bih1s[tid] = bih1[n];
  }
  __syncthreads();

  // ---- prologue: nh0(0) (t=0: agg=h=0, gh=bhh) ----
  if (tid < 8) {
    int c = tid, hcol = c0 + c;
    const float* gi = gi0_all + (size_t)(gb * kT) * 768;
    float r = f_sig(gi[hcol] + bhh0s[c]);
    float u = f_sig(gi[256 + hcol] + bhh0s[8 + c]);
    float n = f_tanh(gi[512 + hcol] + r * bhh0s[16 + c]);
    float val = (1.f - u) * n;
    tape0_s[0][c] = f2bfu(val);
    float other = __shfl_xor(val, 1);   // partner col c^1
    if ((c & 1) == 0) {
      unsigned long long pk = (unsigned long long)f2u(val) |
                              ((unsigned long long)f2u(other) << 32);
      astore64(&nh0p[(size_t)(gb * kT) * 128 + bidg * 4 + (c >> 1)], pk);
    }
  }

  const float SCL = 65536.f;                  // fixed-point scale 2^16
  const float fxi = 1.44269504f / 65536.f;    // log2(e)/2^16

  for (int k = 0; k < kT; ++k) {
    // ======= phase A (single packed nh poll/thread, zero next-parity) =======
    if (tid < 256) {
      int which = tid >> 7;               // 0: nh0(k), 1: nh1(k-1)
      int pr = tid & 127, h = pr * 2;
      if (which == 0) {
        const unsigned long long* p = &nh0p[(size_t)(gb * kT + k) * 128 + pr];
        unsigned long long v = aload64(p);
        int it = 0;
        while (v == CANARY) {
          v = aload64(p);
          if (++it > (1 << 24)) break;   // fail loud, not hang
        }
        float lo = u2f((unsigned int)v), hi = u2f((unsigned int)(v >> 32));
        nh0_s[h] = lo; nh0_s[h + 1] = hi;
        float2 ce2 = *(const float2*)&ce_all[(size_t)(gb * kT + k) * 256 + h];
        li1_s[h]     = fmaxf(lo + ce2.x, 0.f);
        li1_s[h + 1] = fmaxf(hi + ce2.y, 0.f);
      } else if (k > 0) {
        const unsigned long long* p = &nh1p[(size_t)(gb * kT + k - 1) * 128 + pr];
        unsigned long long v = aload64(p);
        int it = 0;
        while (v == CANARY) {
          v = aload64(p);
          if (++it > (1 << 24)) break;
        }
        nh1_s[h]     = u2f((unsigned int)v);
        nh1_s[h + 1] = u2f((unsigned int)(v >> 32));
      }
    }
    // prefetch gi0 row k+1 for the GRU-update phase
    if (tid >= 256 && tid < 264 && k < kT - 1) {
      int c = tid - 256, hcol = c0 + c;
      const float* gi = gi0_all + (size_t)(gb * kT + k + 1) * 768;
      gipre_s[0][c] = gi[hcol];
      gipre_s[1][c] = gi[256 + hcol];
      gipre_s[2][c] = gi[512 + hcol];
    }
    // zero score slots of parity (k+1)%3 (used at step k+1; last read step k-2)
    if (tid >= NTHR - 8) {
      int z = tid - (NTHR - 8);
      int pz = (k + 1) % 3;
      int idx = bidg * 4 + (z & 3);     // 32 blocks x 4 = 128 slots
      if (z < 4) astore64(&S0[pz * 128 + idx], 0ull);
      else       astore64(&S1[pz * 128 + idx], 0ull);
    }
    __syncthreads();

    {   // 112 GEMVs split across 448 threads (p = tid>>2, strided quarters)
      int p = tid >> 2, q = tid & 3;
      if (p < 40) {
        if (k < kT - 1) {
          if (p < 8) {                // hw0 (+bth) + xw0 -> xps0
            int c = p;
            float acc = dot_bf64s(nh0_s, Wth0c[c], q);
            acc += __shfl_xor(acc, 1); acc += __shfl_xor(acc, 2);
            if (q == 0) {
              float xw = xw0_all[(size_t)(gb * kT + k + 1) * kA + c0 + c];
              xps0_s[c] = acc + bth0s[c] + xw;
            }
          } else if (p < 16) {        // tape@Wh0 row k (own cols, +bh)
            int c = p - 8;
            float acc = dot_bf64s(nh0_s, Wh0c[c], q);
            acc += __shfl_xor(acc, 1); acc += __shfl_xor(acc, 2);
            if (q == 0) tWh0_s[k][c] = f2bfu(acc + bh0s[c]);
          } else {                    // tape@Whh0 row k
            int cc = p - 16;
            float acc = dot_bf64s(nh0_s, Whh0c[cc], q);
            acc += __shfl_xor(acc, 1); acc += __shfl_xor(acc, 2);
            if (q == 0) tWhh0_s[k][cc] = f2bfu(acc);
          }
        }
      } else if (p < 72) {
        if (p < 64) {                 // gi1 = li1@Wih1 (+bih)
          int cc = p - 40;
          float acc = dot_bf64s(li1_s, Wih1c[cc], q);
          acc += __shfl_xor(acc, 1); acc += __shfl_xor(acc, 2);
          if (q == 0) gi1_s[cc] = acc + bih1s[cc];
        } else {                      // xw1 = li1@Wx1 (+bx)
          int c = p - 64;
          float acc = dot_bf64s(li1_s, Wx1c[c], q);
          acc += __shfl_xor(acc, 1); acc += __shfl_xor(acc, 2);
          if (q == 0) xps1a_s[c] = acc + bx1s[c];
        }
      } else if (p < 112) {
        if (k > 0) {
          if (p < 80) {               // hw1 (+bth)
            int c = p - 72;
            float acc = dot_bf64s(nh1_s, Wth1c[c], q);
            acc += __shfl_xor(acc, 1); acc += __shfl_xor(acc, 2);
            if (q == 0) xps1b_s[c] = acc + bth1s[c];
          } else if (p < 88) {        // tape@Wh1 row k-1 (+bh)
            int c = p - 80;
            float acc = dot_bf64s(nh1_s, Wh1c[c], q);
            acc += __shfl_xor(acc, 1); acc += __shfl_xor(acc, 2);
            if (q == 0) tWh1_s[k - 1][c] = f2bfu(acc + bh1s[c]);
          } else {                    // tape@Whh1 row k-1
            int cc = p - 88;
            float acc = dot_bf64s(nh1_s, Whh1c[cc], q);
            acc += __shfl_xor(acc, 1); acc += __shfl_xor(acc, 2);
            if (q == 0) tWhh1_s[k - 1][cc] = f2bfu(acc);
          }
        }
      }
    }
    __syncthreads();

    {   // partial scores over own 8 a-cols; count-embedded u64 atomic reduce
      int cnt0w = k + 1, cnt1w = k;
      int np0 = (k < kT - 1) ? ((cnt0w + 1) >> 1) : 0;   // j-pairs, <=128
      int np1 = (cnt1w + 1) >> 1;
      int pk = k % 3;
      unsigned long long* d0 = S0 + pk * 128;
      unsigned long long* d1 = S1 + pk * 128;
      for (int pp = tid; pp < np0 + np1; pp += NTHR) {
        float p0, p1; unsigned long long* dst;
        if (pp < np0) {
          int j0 = 2 * pp;
          p0 = sc4(&tWh0_s[j0][0], xps0_s, v0s) + sc4(&tWh0_s[j0][4], xps0_s + 4, v0s + 4);
          p1 = 0.f;
          if (j0 + 1 < cnt0w)
            p1 = sc4(&tWh0_s[j0 + 1][0], xps0_s, v0s) + sc4(&tWh0_s[j0 + 1][4], xps0_s + 4, v0s + 4);
          dst = d0 + pp;
        } else {
          int pr = pp - np0, j0 = 2 * pr;
          float xp[8];
#pragma unroll
          for (int c = 0; c < 8; ++c) xp[c] = xps1a_s[c] + xps1b_s[c];
          p0 = sc4(&tWh1_s[j0][0], xp, v1s) + sc4(&tWh1_s[j0][4], xp + 4, v1s + 4);
          p1 = 0.f;
          if (j0 + 1 < cnt1w)
            p1 = sc4(&tWh1_s[j0 + 1][0], xp, v1s) + sc4(&tWh1_s[j0 + 1][4], xp + 4, v1s + 4);
          dst = d1 + pr;
        }
        int q0 = (int)rintf(p0 * SCL) + SBIAS;
        int q1 = (int)rintf(p1 * SCL) + SBIAS;
        unsigned long long add = (unsigned long long)(unsigned int)q0 |
                                 ((unsigned long long)(unsigned int)q1 << 32);
        __hip_atomic_fetch_add(dst, add, __ATOMIC_RELAXED, __HIP_MEMORY_SCOPE_AGENT);
      }
    }
    __syncthreads();   // park fast waves until all atomics are issued

    // ================= phase B (dataflow — 128 lanes per softmax row) =======
    int cnt0 = (k < kT - 1) ? (k + 1) : 0;
    int cnt1 = k;
    if (tid < 256) {   // exp(score) + per-row sum; each lane owns one u64 slot
      int r = tid >> 7, lane = tid & 127;
      float sum = 0.f;
      int cnt = (r == 0) ? cnt0 : cnt1;
      if (cnt) {
        int pk = k % 3;
        const unsigned long long* sb = (r == 0) ? S0 + pk * 128 : S1 + pk * 128;
        int npr = (cnt + 1) >> 1;    // <= 128
        if (lane < npr) {
          unsigned long long v = aload64(&sb[lane]);
          int it = 0;
          while (!sready(v)) {
            v = aload64(&sb[lane]);
            if (++it > (1 << 24)) break;   // fail loud, not hang
          }
          int lo = (int)(unsigned int)(v & 0xffffffffull) - SBIAS_TOT;
          int hi = (int)(unsigned int)(v >> 32) - SBIAS_TOT;
          float e0 = fexp2((float)lo * fxi);
          sm_s[r][2 * lane] = e0; sum += e0;
          if (2 * lane + 1 < cnt) {
            float e1 = fexp2((float)hi * fxi);
            sm_s[r][2 * lane + 1] = e1; sum += e1;
          }
        }
      }
      for (int m = 32; m >= 1; m >>= 1) sum += __shfl_xor(sum, m);
      if ((tid & 63) == 0) redsum_s[r][(tid >> 6) & 1] = sum;
    }
    __syncthreads();

    {   // fused gh (=sum w*tapeWhh) and agg (=sum w*tape), own cols; 8 subs
      int slot = tid >> 3, sub = tid & 7;
      float accA = 0.f, accB = 0.f;
      if (slot < 24) {
        if (cnt0) {
          int cc = slot;
#pragma unroll 4
          for (int j = sub; j < cnt0; j += 16) accA += sm_s[0][j] * bfu2f(tWhh0_s[j][cc]);
#pragma unroll 4
          for (int j = sub + 8; j < cnt0; j += 16) accB += sm_s[0][j] * bfu2f(tWhh0_s[j][cc]);
          float acc = accA + accB;
          acc += __shfl_xor(acc, 1); acc += __shfl_xor(acc, 2); acc += __shfl_xor(acc, 4);
          if (sub == 0) gh0_s[cc] = acc * frcp(redsum_s[0][0] + redsum_s[0][1]) + bhh0s[cc];
        }
      } else if (slot < 32) {
        if (cnt0) {
          int c = slot - 24;
#pragma unroll 4
          for (int j = sub; j < cnt0; j += 16) accA += sm_s[0][j] * bfu2f(tape0_s[j][c]);
#pragma unroll 4
          for (int j = sub + 8; j < cnt0; j += 16) accB += sm_s[0][j] * bfu2f(tape0_s[j][c]);
          float acc = accA + accB;
          acc += __shfl_xor(acc, 1); acc += __shfl_xor(acc, 2); acc += __shfl_xor(acc, 4);
          if (sub == 0) agg0_s[c] = acc * frcp(redsum_s[0][0] + redsum_s[0][1]);
        }
      } else if (slot < 56) {
        if (cnt1) {
          int cc = slot - 32;
#pragma unroll 4
          for (int j = sub; j < cnt1; j += 16) accA += sm_s[1][j] * bfu2f(tWhh1_s[j][cc]);
#pragma unroll 4
          for (int j = sub + 8; j < cnt1; j += 16) accB += sm_s[1][j] * bfu2f(tWhh1_s[j][cc]);
          float acc = accA + accB;
          acc += __shfl_xor(acc, 1); acc += __shfl_xor(acc, 2); acc += __shfl_xor(acc, 4);
          if (sub == 0) gh1_s[cc] = acc * frcp(redsum_s[1][0] + redsum_s[1][1]) + bhh1s[cc];
        }
      } else if (slot < 64) {
        if (cnt1) {
          int c = slot - 56;
#pragma unroll 4
          for (int j = sub; j < cnt1; j += 16) accA += sm_s[1][j] * bfu2f(tape1_s[j][c]);
#pragma unroll 4
          for (int j = sub + 8; j < cnt1; j += 16) accB += sm_s[1][j] * bfu2f(tape1_s[j][c]);
          float acc = accA + accB;
          acc += __shfl_xor(acc, 1); acc += __shfl_xor(acc, 2); acc += __shfl_xor(acc, 4);
          if (sub == 0) agg1_s[c] = acc * frcp(redsum_s[1][0] + redsum_s[1][1]);
        }
      }
    }
    __syncthreads();

    // GRU updates (two waves in parallel); publish packed nh pairs
    if (tid < 8) {             // L0 -> nh0(k+1)
      if (k < kT - 1) {
        int c = tid, hcol = c0 + c, t0 = k + 1;
        float agg = agg0_s[c];
        float r = f_sig(gipre_s[0][c] + gh0_s[c]);
        float u = f_sig(gipre_s[1][c] + gh0_s[8 + c]);
        float n = f_tanh(gipre_s[2][c] + r * gh0_s[16 + c]);
        float val = (1.f - u) * n + u * agg;
        tape0_s[t0][c] = f2bfu(val);
        if (t0 == kT - 1) out_tail[gb * kH + hcol] = val;     // h0 final
        float other = __shfl_xor(val, 1);
        if ((c & 1) == 0) {
          unsigned long long pk = (unsigned long long)f2u(val) |
                                  ((unsigned long long)f2u(other) << 32);
          astore64(&nh0p[(size_t)(gb * kT + t0) * 128 + bidg * 4 + (c >> 1)], pk);
        }
      }
    } else if (tid >= 64 && tid < 72) {   // L1 -> nh1(k)
      int c = tid - 64, hcol = c0 + c;
      float ghr, ghu, ghn, agg;
      if (k > 0) { ghr = gh1_s[c]; ghu = gh1_s[8 + c]; ghn = gh1_s[16 + c]; agg = agg1_s[c]; }
      else       { ghr = bhh1s[c]; ghu = bhh1s[8 + c]; ghn = bhh1s[16 + c]; agg = 0.f; }
      float r = f_sig(gi1_s[c] + ghr);
      float u = f_sig(gi1_s[8 + c] + ghu);
      float n = f_tanh(gi1_s[16 + c] + r * ghn);
      float val = (1.f - u) * n + u * agg;
      tape1_s[k][c] = f2bfu(val);
      cat1_all[(size_t)(gb * kT + k) * 512 + hcol] = val;
      if (k == kT - 1) out_tail[kB * kH + gb * kH + hcol] = val;   // h1 final
      float other = __shfl_xor(val, 1);
      if ((c & 1) == 0) {
        unsigned long long pk = (unsigned long long)f2u(val) |
                                ((unsigned long long)f2u(other) << 32);
        astore64(&nh1p[(size_t)(gb * kT + k) * 128 + bidg * 4 + (c >> 1)], pk);
      }
    }
    // no loop-end __syncthreads: next phase A writes disjoint LDS arrays and
    // its own __syncthreads orders them before any cross-phase reads.
  }
}

// ---------------- launch -----------------------------------------------------
extern "C" void kernel_launch(void* const* d_in, const int* in_sizes, int n_in,
                              void* d_out, int out_size, void* d_ws, size_t ws_size,
                              hipStream_t stream) {
  const int*   input_ids    = (const int*)d_in[0];
  const int*   category_ids = (const int*)d_in[1];
  const float* emb     = (const float*)d_in[2];
  const float* cat_emb = (const float*)d_in[3];
  const float* Wih0 = (const float*)d_in[4];
  const float* bih0 = (const float*)d_in[5];
  const float* Whh0 = (const float*)d_in[6];  const float* bhh0 = (const float*)d_in[7];
  const float* Wh0  = (const float*)d_in[8];  const float* bh0  = (const float*)d_in[9];
  const float* Wx0  = (const float*)d_in[10]; const float* bx0  = (const float*)d_in[11];
  const float* Wth0 = (const float*)d_in[12]; const float* bth0 = (const float*)d_in[13];
  const float* v0   = (const float*)d_in[14];
  const float* Wih1 = (const float*)d_in[16]; const float* bih1 = (const float*)d_in[17];
  const float* Whh1 = (const float*)d_in[18]; const float* bhh1 = (const float*)d_in[19];
  const float* Wh1  = (const float*)d_in[20]; const float* bh1  = (const float*)d_in[21];
  const float* Wx1  = (const float*)d_in[22]; const float* bx1  = (const float*)d_in[23];
  const float* Wth1 = (const float*)d_in[24]; const float* bth1 = (const float*)d_in[25];
  const float* v1   = (const float*)d_in[26];
  const float* Wctx = (const float*)d_in[28]; const float* bctx = (const float*)d_in[29];
  const float* Wout = (const float*)d_in[30]; const float* bout = (const float*)d_in[31];

  float* ws = (float*)d_ws;
  float* li0_all  = ws;                    // [1024][512] region (score bufs overlay)
  float* ce_all   = li0_all + 524288;      // [1024][256]
  float* gi0_all  = ce_all + 262144;       // [1024][768]
  float* xw0_all  = gi0_all + 786432;      // [1024][256]
  unsigned long long* nh0p = (unsigned long long*)(xw0_all + 262144);  // [B*T][128] u64
  unsigned long long* nh1p = nh0p + 131072;                            // [B*T][128] u64
  float* cat1_all = (float*)(nh1p + 131072);   // [1024][512]
  unsigned short* ctx_bf = (unsigned short*)(cat1_all + 524288);  // [1024][512] bf16
  unsigned short* li0bf  = ctx_bf + 524288;                       // [1024][512] bf16

  // per-group score buffers OVERLAY the li0_all region (unused otherwise)
  unsigned long long* s0buf = (unsigned long long*)li0_all;  // [4 grp][3 par][128]
  unsigned long long* s1buf = s0buf + 1536;                  // same
  int    nzero_s  = 2 * 1536 * 2;          // scores, in ints
  int    nfill_nh = 2 * 131072 * 2;        // nh0p+nh1p, in ints

  float* out = (float*)d_out;
  float* out_tail = out + (size_t)kB * kT * kV;

  embed_kernel<<<dim3(kB * kT), dim3(256), 0, stream>>>(input_ids, category_ids, emb, cat_emb,
                                                        li0bf, ce_all, cat1_all);
  gemm_mfma_f32out<<<dim3(12, 16), dim3(256), 0, stream>>>(li0bf, Wih0, bih0, gi0_all, 768);
  gemm_mfma_f32out<<<dim3(4, 16), dim3(256), 0, stream>>>(li0bf, Wx0, bx0, xw0_all, 256);
  init_kernel<<<dim3(8), dim3(512), 0, stream>>>((int*)s0buf, nzero_s, 0);
  init_kernel<<<dim3(128), dim3(512), 0, stream>>>((int*)nh0p, nfill_nh, -1);       // NaN canary
  coop_kernel<<<dim3(NBLKS), dim3(NTHR), 0, stream>>>(gi0_all, xw0_all, ce_all, nh0p, nh1p,
      cat1_all, out_tail, s0buf, s1buf,
      Whh0, bhh0, Wh0, bh0, Wth0, bth0, v0,
      Wih1, bih1, Whh1, bhh1, Wh1, bh1, Wx1, bx1, Wth1, bth1, v1);
  gemm_ctx_bf16<<<dim3(8, 16), dim3(256), 0, stream>>>(cat1_all, Wctx, bctx, ctx_bf);
  gemm_logits_mfma<<<dim3(500), dim3(256), 0, stream>>>(ctx_bf, Wout, bout, out);
}